// Round 12
// baseline (280.934 us; speedup 1.0000x reference)
//
#include <hip/hip_runtime.h>

#define SEQ 128
#define BSZ 64
#define EMB 32
#define HD  8
#define VOC 32000
#define NPOS (SEQ * BSZ)          // 8192 positions
#define NRB  (NPOS / 32)          // 256 row-blocks of 32 positions
#define NVS  40                   // v-splits for lse_partial (25 tiles/wave)
#define TPW  25
#define NVSO 50                   // v-splits for out kernel (20 tiles/wave)
#define TPWO 20

typedef float f32x4  __attribute__((ext_vector_type(4)));
typedef short bf16x8 __attribute__((ext_vector_type(8)));
typedef float f32x16 __attribute__((ext_vector_type(16)));

// round-to-nearest-even f32 -> bf16 bits
__device__ __forceinline__ unsigned short f2bf(float f) {
    union { float f; unsigned int u; } x; x.f = f;
    unsigned int r = x.u + 0x7fffu + ((x.u >> 16) & 1u);
    return (unsigned short)(r >> 16);
}

// ---------------------------------------------------------------------------
// Kernel A (fused prep):
//  blocks [0,32):   xproj = lookup[idx] @ Wx + b1 + b2 (both dirs),
//                   thread-contiguous, backward copy time-reversed.
//  blocks [32,157): wt = bf16(Wo^T)  [32000][16]
// ---------------------------------------------------------------------------
__global__ __launch_bounds__(256) void prep_kernel(
    const int*   __restrict__ idx,
    const float* __restrict__ lookup,
    const float* __restrict__ Wxf, const float* __restrict__ Wxb,
    const float* __restrict__ bf1, const float* __restrict__ bf2,
    const float* __restrict__ bb1, const float* __restrict__ bb2,
    const float* __restrict__ Wo,
    float* __restrict__ xpf, float* __restrict__ xpb,
    unsigned short* __restrict__ wt)
{
    if (blockIdx.x < 32) {
        const int i = blockIdx.x * 256 + threadIdx.x;   // flat (s*B + b)
        const int s = i >> 6;
        const int b = i & 63;

        const float* xr = lookup + (size_t)idx[i] * EMB;
        float x[EMB];
#pragma unroll
        for (int e = 0; e < EMB; ++e) x[e] = xr[e];

#pragma unroll
        for (int h = 0; h < HD; ++h) {
            float af = bf1[h] + bf2[h];
            float ab = bb1[h] + bb2[h];
#pragma unroll
            for (int e = 0; e < EMB; ++e) {
                af = fmaf(x[e], Wxf[e * HD + h], af);
                ab = fmaf(x[e], Wxb[e * HD + h], ab);
            }
            xpf[(b * HD + h) * SEQ + s]             = af;
            xpb[(b * HD + h) * SEQ + (SEQ - 1 - s)] = ab;
        }
    } else {
        const int v = (blockIdx.x - 32) * 256 + threadIdx.x;
        if (v < VOC) {
#pragma unroll
            for (int k = 0; k < 16; ++k)
                wt[v * 16 + k] = f2bf(Wo[k * VOC + v]);
        }
    }
}

// ---------------------------------------------------------------------------
// Kernel B: serial recurrence, pure-register; emits bf16 Hcat (hc2[pos][16]).
// ---------------------------------------------------------------------------
__global__ __launch_bounds__(512) void rnn_scan_kernel(
    const float* __restrict__ xpf, const float* __restrict__ xpb,
    const float* __restrict__ Whf, const float* __restrict__ Whb,
    const float* __restrict__ Hf0, const float* __restrict__ Hb0,
    unsigned short* __restrict__ hc2)
{
    const int dir = blockIdx.x;
    const int tid = threadIdx.x;
    const int b   = tid >> 3;
    const int h   = tid & 7;

    const float* Wh = dir ? Whb : Whf;
    const float* xp = (dir ? xpb : xpf) + (size_t)tid * SEQ;

    float wh[HD];
#pragma unroll
    for (int j = 0; j < HD; ++j) wh[j] = Wh[j * HD + h];

    float xs[SEQ];
    const f32x4* xp4 = (const f32x4*)xp;
#pragma unroll
    for (int q = 0; q < SEQ / 4; ++q) {
        f32x4 v = xp4[q];
        xs[4 * q + 0] = v.x; xs[4 * q + 1] = v.y;
        xs[4 * q + 2] = v.z; xs[4 * q + 3] = v.w;
    }

    float hcur = dir ? Hb0[h] : Hf0[h];
    const int koff = dir ? HD : 0;

#pragma unroll
    for (int t = 0; t < SEQ; ++t) {
        const int s = dir ? (SEQ - 1 - t) : t;
        hc2[(s * BSZ + b) * 16 + koff + h] = f2bf(hcur);   // previous state

        float acc = xs[t];
#pragma unroll
        for (int j = 0; j < HD; ++j)
            acc = fmaf(__shfl(hcur, j, 8), wh[j], acc);

        float e = __expf(2.0f * acc);
        hcur = (e - 1.0f) / (e + 1.0f);
    }
}

// ---------------------------------------------------------------------------
// Kernel C: partial exp-sums. Wave = (row-block rb, v-split vs); 25 v-tiles.
// MFMA 32x32x16 bf16 D layout: col=lane&31, row=(g&3)+8*(g>>2)+4*(lane>>5).
// ---------------------------------------------------------------------------
__global__ __launch_bounds__(256) void lse_partial_kernel(
    const unsigned short* __restrict__ hc2,
    const unsigned short* __restrict__ wt,
    const float* __restrict__ bo,
    float* __restrict__ partial)
{
    const int gw   = blockIdx.x * 4 + (threadIdx.x >> 6);   // global wave id
    const int rb   = gw / NVS;
    const int vs   = gw - rb * NVS;
    const int lane = threadIdx.x & 63;
    const int half = lane >> 5;
    const int lc   = lane & 31;

    const bf16x8 afrag = *(const bf16x8*)(hc2 + (size_t)(rb * 32 + lc) * 16 + half * 8);

    f32x16 zv;
#pragma unroll
    for (int i = 0; i < 16; ++i) zv[i] = 0.0f;

    float sacc[16];
#pragma unroll
    for (int g = 0; g < 16; ++g) sacc[g] = 0.0f;

    for (int t = 0; t < TPW; ++t) {
        const int v0 = (vs * TPW + t) * 32;
        const bf16x8 bfrag = *(const bf16x8*)(wt + (size_t)(v0 + lc) * 16 + half * 8);
        f32x16 d = __builtin_amdgcn_mfma_f32_32x32x16_bf16(afrag, bfrag, zv, 0, 0, 0);
        const float bov = bo[v0 + lc];
#pragma unroll
        for (int g = 0; g < 16; ++g)
            sacc[g] += __expf(d[g] + bov);
    }

    // reduce each sacc[g] across the 32 lanes of this half
#pragma unroll
    for (int g = 0; g < 16; ++g) {
        float s = sacc[g];
        s += __shfl_xor(s, 1, 32);
        s += __shfl_xor(s, 2, 32);
        s += __shfl_xor(s, 4, 32);
        s += __shfl_xor(s, 8, 32);
        s += __shfl_xor(s, 16, 32);
        sacc[g] = s;
    }

    if (lc == 0) {
#pragma unroll
        for (int g = 0; g < 16; ++g) {
            const int row = (g & 3) + 8 * (g >> 2) + 4 * half;
            partial[(size_t)(rb * 32 + row) * NVS + vs] = sacc[g];
        }
    }
}

// ---------------------------------------------------------------------------
// Kernel D: lse[row] = log( sum_vs partial[row][vs] )
// ---------------------------------------------------------------------------
__global__ __launch_bounds__(256) void lse_reduce_kernel(
    const float* __restrict__ partial, float* __restrict__ lse)
{
    const int row = blockIdx.x * 256 + threadIdx.x;
    if (row >= NPOS) return;
    const f32x4* p4 = (const f32x4*)(partial + (size_t)row * NVS);
    float s = 0.0f;
#pragma unroll
    for (int q = 0; q < NVS / 4; ++q) {
        f32x4 v = p4[q];
        s += v.x + v.y + v.z + v.w;
    }
    lse[row] = logf(s);
}

// ---------------------------------------------------------------------------
// Kernel E: out = logits - lse via MFMA; output staged through a SMALL
// per-wave LDS tile (2 v-tiles at a time -> 32 KB/block -> 5 blocks/CU,
// 20 waves/CU) then streamed as wide contiguous plain stores (1 KB per
// store instruction, 256 B runs). Combines R10's store width with R9's
// occupancy: the store pipe stays fed while other waves compute.
// Wave = (rb, vs in 50 splits of 20 tiles).
// ---------------------------------------------------------------------------
__global__ __launch_bounds__(256) void out_mfma_kernel(
    const unsigned short* __restrict__ hc2,
    const unsigned short* __restrict__ wt,
    const float* __restrict__ bo,
    const float* __restrict__ lse,
    float* __restrict__ out)
{
    __shared__ float lbuf[4][32][64];   // 32 KB; per-wave private slice

    const int w    = threadIdx.x >> 6;
    const int gw   = blockIdx.x * 4 + w;
    const int rb   = gw / NVSO;
    const int vs   = gw - rb * NVSO;
    const int lane = threadIdx.x & 63;
    const int half = lane >> 5;
    const int lc   = lane & 31;

    const bf16x8 afrag = *(const bf16x8*)(hc2 + (size_t)(rb * 32 + lc) * 16 + half * 8);

    f32x16 zv;
#pragma unroll
    for (int i = 0; i < 16; ++i) zv[i] = 0.0f;

    // per-lane lse for its 16 (reg) rows
    float lse16[16];
#pragma unroll
    for (int g = 0; g < 16; ++g) {
        const int row = (g & 3) + 8 * (g >> 2) + 4 * half;
        lse16[g] = lse[rb * 32 + row];
    }

    for (int grp = 0; grp < TPWO / 2; ++grp) {
        // ---- compute 2 tiles into the LDS staging tile ----
#pragma unroll
        for (int t2 = 0; t2 < 2; ++t2) {
            const int v0 = (vs * TPWO + grp * 2 + t2) * 32;
            const bf16x8 bfrag = *(const bf16x8*)(wt + (size_t)(v0 + lc) * 16 + half * 8);
            f32x16 d = __builtin_amdgcn_mfma_f32_32x32x16_bf16(afrag, bfrag, zv, 0, 0, 0);
            const float bov = bo[v0 + lc];
#pragma unroll
            for (int g = 0; g < 16; ++g) {
                const int row = (g & 3) + 8 * (g >> 2) + 4 * half;
                lbuf[w][row][t2 * 32 + lc] = d[g] + bov - lse16[g];
            }
        }
        // ---- stream the 32x64 tile out: 8 instrs, each 4 rows x 256 B ----
        // (same-wave LDS write->read dependency; compiler inserts lgkmcnt)
        const size_t obase = (size_t)(rb * 32) * VOC
                           + (size_t)(vs * TPWO + grp * 2) * 32;
#pragma unroll
        for (int i = 0; i < 8; ++i) {
            const int q   = i * 64 + lane;     // quad index 0..511
            const int row = q >> 4;            // 16 quads (64 floats) per row
            const int c   = q & 15;
            const f32x4 v4 = *(const f32x4*)&lbuf[w][row][c * 4];
            *(f32x4*)(out + obase + (size_t)row * VOC + c * 4) = v4;
        }
    }
}

extern "C" void kernel_launch(void* const* d_in, const int* in_sizes, int n_in,
                              void* d_out, int out_size, void* d_ws, size_t ws_size,
                              hipStream_t stream)
{
    const int*   idx    = (const int*)  d_in[0];
    const float* lookup = (const float*)d_in[1];
    const float* Wxf    = (const float*)d_in[2];
    const float* Whf    = (const float*)d_in[3];
    const float* Wxb    = (const float*)d_in[4];
    const float* Whb    = (const float*)d_in[5];
    const float* Wo     = (const float*)d_in[6];
    const float* Hf0    = (const float*)d_in[7];
    const float* Hb0    = (const float*)d_in[8];
    const float* bf1    = (const float*)d_in[9];
    const float* bf2    = (const float*)d_in[10];
    const float* bb1    = (const float*)d_in[11];
    const float* bb2    = (const float*)d_in[12];
    const float* bo     = (const float*)d_in[13];
    float* out = (float*)d_out;

    // workspace layout (all 16B-aligned)
    char* ws = (char*)d_ws;
    float*          xpf     = (float*)ws;          ws += BSZ * HD * SEQ * 4;      // 256 KB
    float*          xpb     = (float*)ws;          ws += BSZ * HD * SEQ * 4;      // 256 KB
    unsigned short* hc2     = (unsigned short*)ws; ws += NPOS * 16 * 2;           // 256 KB
    unsigned short* wt      = (unsigned short*)ws; ws += VOC * 16 * 2;            // 1 MB
    float*          partial = (float*)ws;          ws += (size_t)NPOS * NVS * 4;  // 1.31 MB
    float*          lse     = (float*)ws;          ws += NPOS * 4;                // 32 KB

    hipLaunchKernelGGL(prep_kernel, dim3(32 + VOC / 256), dim3(256), 0, stream,
                       idx, lookup, Wxf, Wxb, bf1, bf2, bb1, bb2, Wo,
                       xpf, xpb, wt);
    hipLaunchKernelGGL(rnn_scan_kernel, dim3(2), dim3(512), 0, stream,
                       xpf, xpb, Whf, Whb, Hf0, Hb0, hc2);
    hipLaunchKernelGGL(lse_partial_kernel, dim3(NRB * NVS / 4), dim3(256), 0, stream,
                       hc2, wt, bo, partial);
    hipLaunchKernelGGL(lse_reduce_kernel, dim3(NPOS / 256), dim3(256), 0, stream,
                       partial, lse);
    hipLaunchKernelGGL(out_mfma_kernel, dim3(NRB * NVSO / 4), dim3(256), 0, stream,
                       hc2, wt, bo, lse, out);
}